// Round 8
// baseline (86.631 us; speedup 1.0000x reference)
//
#include <hip/hip_runtime.h>
#include <math.h>

// Problem constants: B=64, IN=1024, OUT=512, T=512, V_TH=1, TAU=16
#define BATCH   64
#define INS     1024
#define OUTS    512
#define TSTEPS  512
#define TAUF    16.0f
// log2(e)/TAU for exp(t/tau) == exp2(t * LOG2E_OVER_TAU)
#define LOG2E_OVER_TAU 0.0901684400555602f

typedef unsigned int u32;

// ---------------------------------------------------------------------------
// Fused pre-kernel: blocks [0,128) tiled weight transpose w[OUT,IN]->wT[IN,OUT];
// blocks [128,192) per-batch spike prep + counting sort by activation time.
//   alpha(t-s) = e^{-t/tau} * (t*A + C) for t > s,
//   A = exp(1 + s/tau)/tau,  C = -s*A,  t_on = floor(s)+1 in [1,256].
// Record per spike (sorted by t_on): {A, int_bits(i*64 = LDS row byte off),
// C, t_on}.  Also writes starts[b][tau], tau in [0,257].
// ---------------------------------------------------------------------------
#define TT 64
#define NTRANS ((INS / TT) * (OUTS / TT))   // 128 transpose blocks

__global__ __launch_bounds__(256) void pre_kernel(
        const float* __restrict__ w, float* __restrict__ wT,
        const float* __restrict__ in_spike, float4* __restrict__ spk,
        int* __restrict__ starts) {
    __shared__ float tile[TT][TT + 1];
    __shared__ int hist[257];
    __shared__ int cursor[257];
    __shared__ int wsum[4];

    if (blockIdx.x < NTRANS) {
        const int i0 = (blockIdx.x & (INS / TT - 1)) * TT;
        const int o0 = (blockIdx.x / (INS / TT)) * TT;
        const int c  = threadIdx.x & 63;
        const int r  = threadIdx.x >> 6;
#pragma unroll
        for (int rr = r; rr < TT; rr += 4)
            tile[rr][c] = w[(o0 + rr) * INS + i0 + c];
        __syncthreads();
#pragma unroll
        for (int rr = r; rr < TT; rr += 4)
            wT[(i0 + rr) * OUTS + o0 + c] = tile[c][rr];
        return;
    }

    const int b = blockIdx.x - NTRANS;
    const int tid = threadIdx.x;
    for (int k = tid; k < 257; k += 256) hist[k] = 0;
    __syncthreads();

    float sv[INS / 256];
    int   tv[INS / 256];
#pragma unroll
    for (int j = 0; j < INS / 256; ++j) {
        int i = tid + j * 256;
        float s = in_spike[b * INS + i];
        sv[j] = s;
        int t = (int)floorf(s) + 1;
        t = t < 1 ? 1 : (t > 256 ? 256 : t);
        tv[j] = t;
        atomicAdd(&hist[t], 1);
    }
    __syncthreads();

    // wave-shuffle inclusive scan of hist[1..256] across 4 waves
    const int lane = tid & 63;
    const int wv   = tid >> 6;
    int v = hist[tid + 1];
    int sc = v;
#pragma unroll
    for (int off = 1; off < 64; off <<= 1) {
        int n = __shfl_up(sc, off, 64);
        if (lane >= off) sc += n;
    }
    if (lane == 63) wsum[wv] = sc;
    __syncthreads();
    int base = 0;
    for (int j = 0; j < wv; ++j) base += wsum[j];
    int excl = sc + base - v;             // # spikes with t_on < tid+1
    cursor[tid + 1] = excl;
    starts[b * 258 + tid + 1] = excl;
    if (tid == 0) { starts[b * 258] = 0; starts[b * 258 + 257] = INS; }
    __syncthreads();

#pragma unroll
    for (int j = 0; j < INS / 256; ++j) {
        int i = tid + j * 256;
        int t = tv[j];
        int pos = atomicAdd(&cursor[t], 1);
        float A = expf(fmaf(sv[j], 1.0f / TAUF, 1.0f)) * (1.0f / TAUF);
        float C = -sv[j] * A;
        // y holds LDS row byte offset i*64 (row stride in ws[1024][16])
        spk[b * INS + pos] =
            make_float4(A, __int_as_float(i * 64), C, __int_as_float(t));
    }
}

// ---------------------------------------------------------------------------
// Scan kernel, LDS-RESIDENT WEIGHTS, DE-SPILLED (round-8).
//
// R6's double-pass proved the walk cost is structural (warm pass == cold
// pass; VALUBusy 16%; not BW-bound): the dependent global gather chain
// {ds_read -> addr -> gather -> vmcnt -> fma} dominates.  This structure
// (from R5) removes the global gather entirely: the block's 16-column wT
// slice (64 KB) is bulk-staged into LDS with address-independent
// global_load_lds, so the walk touches only LDS (~120cy hops) and each
// thread walks only ~8 spikes (WS=2).
//
// R5's null result was CONFOUNDED: __launch_bounds__(1024, 8) capped the
// allocator at 64 VGPRs -> 32 allocated -> shuffle-scan state spilled to
// scratch (R2/R6 counters: WRITE_SIZE 48/168 MB vs 128 KB logical).
// FIX: min-waves 8 -> 4.  LDS (81 KB) already caps at 1 block/CU, so the
// 128-VGPR budget costs zero occupancy.  Single-variable change vs R5.
//
// Geometry: 1024 thr = x(8 lanes, 2 outputs each, float2 ws reads) x
// g(128 windows, WS=2).  Snapshot walk: bucket0, snapshot l0 at t=w0,
// bucket1, snapshot l1 at t=w0+1.  Scan over g: in-wave shuffle scan ->
// per-wave totals sQ[16][8] -> wave 0 scans 16 wave totals in-register ->
// sQpre[17][8] (exclusive prefixes + grand total).
// Check: V(t_d) = fma(t_d, SexA, SexC) + l_d >= exp2(t_d*log2e/tau).
// Spike-free tail [257,512) split 2 steps per g using totals.  Windows +
// tail partition the time axis; shfl-min over g + atomicMin -> exact.
// Grid = 64 x 32 = 2048 blocks.
// ---------------------------------------------------------------------------
#define OL 8             // lanes per window-group (each owns 2 outputs)
#define G  128           // time windows
#define OBLK 16          // outputs per block
#define TAIL0 257        // first spike-free time step

__global__ __launch_bounds__(OL * G, 4) void spike_scan_kernel(
        const float4* __restrict__ spk, const int* __restrict__ starts,
        const float* __restrict__ wT, float* __restrict__ out) {
    const int b = blockIdx.x;
    const int x = threadIdx.x;           // 0..7 lane group
    const int g = threadIdx.y;           // 0..127 window
    const int tid = g * OL + x;
    const int lane = tid & 63;
    const int gl = lane >> 3;            // window index within wave (0..7)
    const int wv = tid >> 6;             // wave index (0..15)

    __shared__ float  ws[INS][OBLK];     // 64 KB weight slice
    __shared__ float2 sAC[INS];          // 8 KB (A, C)
    __shared__ unsigned short sRowB[INS];// 2 KB row byte offsets
    __shared__ float4 sQ[16][OL];        // 2 KB per-wave inclusive totals
    __shared__ float4 sQpre[17][OL];     // 2.1 KB exclusive prefixes + total
    __shared__ int    sSt[258];          // 1 KB
    __shared__ int    sFirst[OBLK];      // 64 B

    // ---- bulk stage: 16-column weight slice, 4 dwordx4 per thread ----
    // instr s covers row = s*256 + tid/4, j-chunk = tid%4 (4 floats).
    // LDS dst flat = row*64 + (tid%4)*16 = s*16384 + tid*16  (lane-linear).
    {
        const char* srcb = (const char*)wT
            + (size_t)(tid >> 2) * (OUTS * 4)
            + (size_t)blockIdx.y * (OBLK * 4)
            + (size_t)(tid & 3) * 16;
        char* dstb = (char*)ws + (size_t)tid * 16;
#pragma unroll
        for (int s = 0; s < 4; ++s) {
            auto gsrc = (const __attribute__((address_space(1))) u32*)
                            (srcb + (size_t)s * 256 * (OUTS * 4));
            auto ldst = (__attribute__((address_space(3))) u32*)
                            (dstb + s * 16384);
            __builtin_amdgcn_global_load_lds(gsrc, ldst, 16, 0, 0);
        }
    }
    // ---- spike meta: packed (A,C) + row byte offset ----
    {
        float4 p = spk[(size_t)b * INS + tid];
        sAC[tid] = make_float2(p.x, p.z);
        sRowB[tid] = (unsigned short)__float_as_int(p.y);
    }
    if (tid < 258) sSt[tid] = starts[b * 258 + tid];
    if (tid < OBLK) sFirst[tid] = TSTEPS;
    __syncthreads();

    // ---- snapshot walk over this window's two buckets (LDS only) ----
    const int w0 = 2 * g + 1;
    const u32 x8 = (u32)(x << 3);        // this lane's float2 column bytes
    float cA0 = 0.f, cC0 = 0.f, cA1 = 0.f, cC1 = 0.f;
    float l00, l01, l10, l11;
    int k = sSt[w0];
    {
        const int e0 = sSt[w0 + 1];
        for (; k < e0; ++k) {
            float2 ac = sAC[k];
            u32 ro = (u32)sRowB[k];
            const float2 q = *(const float2*)((const char*)ws + ro + x8);
            cA0 = fmaf(q.x, ac.x, cA0); cC0 = fmaf(q.x, ac.y, cC0);
            cA1 = fmaf(q.y, ac.x, cA1); cC1 = fmaf(q.y, ac.y, cC1);
        }
        const float tf = (float)w0;
        l00 = fmaf(tf, cA0, cC0);
        l10 = fmaf(tf, cA1, cC1);
    }
    {
        const int e1 = sSt[w0 + 2];
        for (; k < e1; ++k) {
            float2 ac = sAC[k];
            u32 ro = (u32)sRowB[k];
            const float2 q = *(const float2*)((const char*)ws + ro + x8);
            cA0 = fmaf(q.x, ac.x, cA0); cC0 = fmaf(q.x, ac.y, cC0);
            cA1 = fmaf(q.y, ac.x, cA1); cC1 = fmaf(q.y, ac.y, cC1);
        }
        const float tf = (float)(w0 + 1);
        l01 = fmaf(tf, cA0, cC0);
        l11 = fmaf(tf, cA1, cC1);
    }

    // ---- level 1: in-wave inclusive scan over gl (8 windows/wave) ----
    float sA0 = cA0, sC0 = cC0, sA1 = cA1, sC1 = cC1;
#pragma unroll
    for (int off = 8; off <= 32; off <<= 1) {
        float t0 = __shfl_up(sA0, off);
        float t1 = __shfl_up(sC0, off);
        float t2 = __shfl_up(sA1, off);
        float t3 = __shfl_up(sC1, off);
        if (lane >= off) { sA0 += t0; sC0 += t1; sA1 += t2; sC1 += t3; }
    }
    // exclusive-of-own within wave
    float eA0 = __shfl_up(sA0, 8);
    float eC0 = __shfl_up(sC0, 8);
    float eA1 = __shfl_up(sA1, 8);
    float eC1 = __shfl_up(sC1, 8);
    if (gl == 0) { eA0 = 0.f; eC0 = 0.f; eA1 = 0.f; eC1 = 0.f; }
    if (gl == 7) sQ[wv][x] = make_float4(sA0, sC0, sA1, sC1);
    __syncthreads();

    // ---- level 2: wave 0 scans the 16 wave-totals in-register ----
    if (tid < 64) {
        const int w = tid >> 3, xx = tid & 7;
        float4 q1 = sQ[w][xx];
        float4 q2 = sQ[w + 8][xx];
        float4 s1 = q1, s2 = q2;
#pragma unroll
        for (int off = 8; off <= 32; off <<= 1) {
            float a0 = __shfl_up(s1.x, off), a1 = __shfl_up(s1.y, off);
            float a2 = __shfl_up(s1.z, off), a3 = __shfl_up(s1.w, off);
            float b0 = __shfl_up(s2.x, off), b1 = __shfl_up(s2.y, off);
            float b2 = __shfl_up(s2.z, off), b3 = __shfl_up(s2.w, off);
            if (lane >= off) {
                s1.x += a0; s1.y += a1; s1.z += a2; s1.w += a3;
                s2.x += b0; s2.y += b1; s2.z += b2; s2.w += b3;
            }
        }
        float4 h1;   // inclusive total of waves 0..7 (broadcast from w=7)
        h1.x = __shfl(s1.x, 56 + xx); h1.y = __shfl(s1.y, 56 + xx);
        h1.z = __shfl(s1.z, 56 + xx); h1.w = __shfl(s1.w, 56 + xx);
        sQpre[w][xx] = make_float4(s1.x - q1.x, s1.y - q1.y,
                                   s1.z - q1.z, s1.w - q1.w);
        sQpre[w + 8][xx] = make_float4(h1.x + s2.x - q2.x, h1.y + s2.y - q2.y,
                                       h1.z + s2.z - q2.z, h1.w + s2.w - q2.w);
        if (w == 7)
            sQpre[16][xx] = make_float4(h1.x + s2.x, h1.y + s2.y,
                                        h1.z + s2.z, h1.w + s2.w);
    }
    __syncthreads();

    // ---- checks: V(t_d) = fma(t_d, Sex, SexC) + l_d ----
    const float4 pr = sQpre[wv][x];
    const float4 tt = sQpre[16][x];
    const float SexA0 = pr.x + eA0, SexC0 = pr.y + eC0;
    const float SexA1 = pr.z + eA1, SexC1 = pr.w + eC1;
    int f0 = TSTEPS, f1 = TSTEPS;
    {
        const float tf1 = (float)(w0 + 1);
        const float ev1 = exp2f(tf1 * LOG2E_OVER_TAU);
        if (fmaf(tf1, SexA0, SexC0) + l01 >= ev1) f0 = w0 + 1;
        if (fmaf(tf1, SexA1, SexC1) + l11 >= ev1) f1 = w0 + 1;
        const float tf0 = (float)w0;
        const float ev0 = exp2f(tf0 * LOG2E_OVER_TAU);
        if (fmaf(tf0, SexA0, SexC0) + l00 >= ev0) f0 = w0;
        if (fmaf(tf0, SexA1, SexC1) + l10 >= ev0) f1 = w0;
    }
    // ---- spike-free tail [TAIL0, TSTEPS): 2 steps per g using totals ----
    {
        const int t0i = TAIL0 + 2 * g;            // <= 511
        const float ta0 = (float)t0i;
        const float ta1 = ta0 + 1.0f;
        const float ev0t = exp2f(ta0 * LOG2E_OVER_TAU);
        const float ev1t = exp2f(ta1 * LOG2E_OVER_TAU);
        const bool in1 = (t0i + 1 < TSTEPS);
        bool c00 = fmaf(ta0, tt.x, tt.y) >= ev0t;
        bool c01 = in1 && (fmaf(ta1, tt.x, tt.y) >= ev1t);
        bool c10 = fmaf(ta0, tt.z, tt.w) >= ev0t;
        bool c11 = in1 && (fmaf(ta1, tt.z, tt.w) >= ev1t);
        if (f0 == TSTEPS) f0 = c00 ? t0i : (c01 ? t0i + 1 : TSTEPS);
        if (f1 == TSTEPS) f1 = c10 ? t0i : (c11 ? t0i + 1 : TSTEPS);
    }

    // ---- min-reduce over the 8 windows in this wave, then atomicMin ----
#pragma unroll
    for (int off = 8; off <= 32; off <<= 1) {
        f0 = min(f0, __shfl_xor(f0, off));
        f1 = min(f1, __shfl_xor(f1, off));
    }
    if (gl == 0) {
        if (f0 < TSTEPS) atomicMin(&sFirst[2 * x], f0);
        if (f1 < TSTEPS) atomicMin(&sFirst[2 * x + 1], f1);
    }
    __syncthreads();
    if (tid < OBLK)
        out[b * OUTS + blockIdx.y * OBLK + tid] = (float)sFirst[tid];
}

// ---------------------------------------------------------------------------
extern "C" void kernel_launch(void* const* d_in, const int* in_sizes, int n_in,
                              void* d_out, int out_size, void* d_ws, size_t ws_size,
                              hipStream_t stream) {
    const float* in_spike = (const float*)d_in[0];   // [B, IN] fp32
    const float* weight   = (const float*)d_in[1];   // [OUT, IN] fp32
    float* out = (float*)d_out;                      // [B, OUT] fp32

    // ws layout: wT 2 MB | spk 1 MB | starts 64*258 ints (~66 KB)
    float*  wT     = (float*)d_ws;
    float4* spk    = (float4*)((char*)d_ws + (size_t)INS * OUTS * sizeof(float));
    int*    starts = (int*)((char*)d_ws + (size_t)INS * OUTS * sizeof(float)
                                        + (size_t)BATCH * INS * sizeof(float4));

    pre_kernel<<<NTRANS + BATCH, 256, 0, stream>>>(weight, wT, in_spike, spk, starts);
    spike_scan_kernel<<<dim3(BATCH, OUTS / OBLK), dim3(OL, G), 0, stream>>>(
        spk, starts, wT, out);
}